// Round 2
// baseline (45.060 us; speedup 1.0000x reference)
//
#include <hip/hip_runtime.h>

#define NG  8     // groups (heads)
#define DH  8     // channels per group
#define KS  7
#define PAD 3
#define TH  16    // tile height (output rows per block)
#define TW  32    // tile width (output cols per block)
#define OW  2     // outputs per thread along W
#define TPH 22    // padded tile rows (TH + KS - 1)
#define TPW 38    // padded tile cols (TW + KS - 1)
#define LST 40    // LDS row stride in words (mult of 4; stride%32=8 -> even bank spread)
#define CH  64
#define HH  64
#define WW  64

__device__ __forceinline__ int imin(int a, int b) { return a < b ? a : b; }
__device__ __forceinline__ int imax(int a, int b) { return a > b ? a : b; }

__global__ __launch_bounds__(256, 2)
void saconv_kernel(const float* __restrict__ x,
                   const float* __restrict__ wq,
                   const float* __restrict__ wk,
                   const float* __restrict__ wv,
                   const float* __restrict__ relh,
                   const float* __restrict__ relw,
                   float* __restrict__ out) {
  __shared__ float xs[DH][TPH * LST];   // zero-padded x tile, 27.5 KB
  __shared__ float swq[DH * DH];
  __shared__ float swk[DH * DH];
  __shared__ float swv[DH * DH];
  __shared__ float srel[DH * KS];       // rel table for this group's channels

  const int tx  = threadIdx.x;          // 0..15 (pair of output columns)
  const int ty  = threadIdx.y;          // 0..15 (output row)
  const int tid = ty * 16 + tx;         // 0..255
  const int bz  = blockIdx.z;
  const int b   = bz >> 3;
  const int g   = bz & 7;
  const int h0  = blockIdx.y * TH;
  const int w0  = blockIdx.x * TW;

  // ---- stage weights + rel table ----
  if (tid < DH * DH) swq[tid] = wq[g * DH * DH + tid];
  else if (tid < 2 * DH * DH) swk[tid - 64] = wk[g * DH * DH + tid - 64];
  else if (tid < 3 * DH * DH) swv[tid - 128] = wv[g * DH * DH + tid - 128];
  else if (tid < 3 * DH * DH + DH * KS) {
    int t2 = tid - 192;
    int c = t2 / KS, t = t2 - c * KS;
    int gc = g * DH + c;               // global channel
    srel[t2] = (g < 4) ? relh[gc * KS + t] : relw[(gc - 32) * KS + t];
  }

  // ---- stage zero-padded x tile as float4 chunks ----
  // xs[ci][row*LST + col] = x[b, g*8+ci, h0+row-3, w0+col-3]; cols 0..39 staged (38 used)
  const float* xb = x + (size_t)(b * CH + g * DH) * (HH * WW);
  const int NF4 = DH * TPH * (LST / 4);   // 8*22*10 = 1760 float4 chunks
  #pragma unroll
  for (int kk = 0; kk < 7; kk++) {
    int f = tid + kk * 256;
    if (f < NF4) {
      int ci  = f / (TPH * 10);
      int r   = f - ci * (TPH * 10);
      int row = r / 10;
      int c4  = r - row * 10;
      int yy  = h0 + row - PAD;
      int cy  = imin(imax(yy, 0), HH - 1);
      bool yok = (yy >= 0) & (yy < HH);
      float v[4];
      #pragma unroll
      for (int e = 0; e < 4; e++) {
        int xx = w0 + 4 * c4 + e - PAD;
        int cx = imin(imax(xx, 0), WW - 1);
        bool inb = yok & (xx >= 0) & (xx < WW);
        float t = xb[(ci * HH + cy) * WW + cx];
        v[e] = inb ? t : 0.0f;
      }
      *(float4*)(&xs[ci][row * LST + 4 * c4]) = make_float4(v[0], v[1], v[2], v[3]);
    }
  }
  __syncthreads();

  // ---- q for this thread's 2 outputs, fold: qk = Wk^T q, rq = rel^T q ----
  float qk[OW][DH];
  float rq[OW][KS];
  {
    float q_[OW][DH];
    #pragma unroll
    for (int o = 0; o < OW; o++) {
      float xc[DH];
      #pragma unroll
      for (int ci = 0; ci < DH; ci++)
        xc[ci] = xs[ci][(ty + PAD) * LST + 2 * tx + o + PAD];
      #pragma unroll
      for (int c = 0; c < DH; c++) {
        float a = 0.f;
        #pragma unroll
        for (int ci = 0; ci < DH; ci++)
          a = fmaf(swq[c * DH + ci], xc[ci], a);
        q_[o][c] = a;
      }
    }
    #pragma unroll
    for (int o = 0; o < OW; o++)
      #pragma unroll
      for (int ci = 0; ci < DH; ci++) {
        float a = 0.f;
        #pragma unroll
        for (int c = 0; c < DH; c++)
          a = fmaf(q_[o][c], swk[c * DH + ci], a);
        qk[o][ci] = a;
      }
    #pragma unroll
    for (int o = 0; o < OW; o++)
      #pragma unroll
      for (int t = 0; t < KS; t++) {
        float a = 0.f;
        #pragma unroll
        for (int c = 0; c < DH; c++)
          a = fmaf(q_[o][c], srel[c * KS + t], a);
        rq[o][t] = a;
      }
  }

  // ---- online-softmax window loop ----
  const float scale = 0.35355339059327373f;  // sqrt(g/Cout) = sqrt(1/8)
  const bool useI = (g < 4);                 // rel_h half -> rel depends on window row i

  float m[OW], s[OW], xa[OW][DH];
  #pragma unroll
  for (int o = 0; o < OW; o++) {
    m[o] = -1e30f;
    s[o] = 0.f;
    #pragma unroll
    for (int ci = 0; ci < DH; ci++) xa[o][ci] = 0.f;
  }

  #pragma unroll
  for (int i = 0; i < KS; i++) {
    const int rowoff = (ty + i) * LST + 2 * tx;   // 8B-aligned word offset
    // load the 8-word row segment for all 8 channels (4x ds_read_b64 each)
    float xr[DH][8];
    #pragma unroll
    for (int ci = 0; ci < DH; ci++) {
      const float* bp = &xs[ci][rowoff];
      float2 a0 = *(const float2*)(bp);
      float2 a1 = *(const float2*)(bp + 2);
      float2 a2 = *(const float2*)(bp + 4);
      float2 a3 = *(const float2*)(bp + 6);
      xr[ci][0] = a0.x; xr[ci][1] = a0.y; xr[ci][2] = a1.x; xr[ci][3] = a1.y;
      xr[ci][4] = a2.x; xr[ci][5] = a2.y; xr[ci][6] = a3.x; xr[ci][7] = a3.y;
    }

    // logits for this window row
    float lg[OW][KS];
    #pragma unroll
    for (int o = 0; o < OW; o++) {
      #pragma unroll
      for (int j = 0; j < KS; j++) {
        float d = 0.f;
        #pragma unroll
        for (int ci = 0; ci < DH; ci++)
          d = fmaf(qk[o][ci], xr[ci][o + j], d);
        lg[o][j] = (d + (useI ? rq[o][i] : rq[o][j])) * scale;
      }
    }

    // online softmax update + weighted-x accumulation
    #pragma unroll
    for (int o = 0; o < OW; o++) {
      float rmax = lg[o][0];
      #pragma unroll
      for (int j = 1; j < KS; j++) rmax = fmaxf(rmax, lg[o][j]);
      float mn   = fmaxf(m[o], rmax);
      float corr = __expf(m[o] - mn);      // first row: exp(-huge) == 0
      m[o] = mn;
      float e[KS], se = 0.f;
      #pragma unroll
      for (int j = 0; j < KS; j++) { e[j] = __expf(lg[o][j] - mn); se += e[j]; }
      s[o] = s[o] * corr + se;
      #pragma unroll
      for (int ci = 0; ci < DH; ci++) {
        float a = xa[o][ci] * corr;
        #pragma unroll
        for (int j = 0; j < KS; j++)
          a = fmaf(e[j], xr[ci][o + j], a);
        xa[o][ci] = a;
      }
    }
  }

  // ---- epilogue: out = Wv * (xa / s), float2 stores ----
  #pragma unroll
  for (int o = 0; o < OW; o++) {
    float inv = 1.0f / s[o];
    #pragma unroll
    for (int ci = 0; ci < DH; ci++) xa[o][ci] *= inv;
  }

  const int h = h0 + ty;
  const int wbase = w0 + 2 * tx;
  #pragma unroll
  for (int c = 0; c < DH; c++) {
    float2 v2;
    {
      float a0 = 0.f, a1 = 0.f;
      #pragma unroll
      for (int ci = 0; ci < DH; ci++) {
        a0 = fmaf(swv[c * DH + ci], xa[0][ci], a0);
        a1 = fmaf(swv[c * DH + ci], xa[1][ci], a1);
      }
      v2.x = a0; v2.y = a1;
    }
    *(float2*)(&out[((size_t)(b * CH + g * DH + c) * HH + h) * WW + wbase]) = v2;
  }
}

extern "C" void kernel_launch(void* const* d_in, const int* in_sizes, int n_in,
                              void* d_out, int out_size, void* d_ws, size_t ws_size,
                              hipStream_t stream) {
  const float* x    = (const float*)d_in[0];
  // d_in[1] = r, unused by the reference computation
  const float* wq   = (const float*)d_in[2];
  const float* wk   = (const float*)d_in[3];
  const float* wv   = (const float*)d_in[4];
  const float* relh = (const float*)d_in[5];
  const float* relw = (const float*)d_in[6];
  float* out = (float*)d_out;

  const int B = in_sizes[0] / (CH * HH * WW);   // 8
  dim3 grid(WW / TW, HH / TH, B * NG);          // 2 x 4 x 64 = 512 blocks
  dim3 block(16, 16, 1);                        // 256 threads = 4 waves
  saconv_kernel<<<grid, block, 0, stream>>>(x, wq, wk, wv, relh, relw, out);
}

// Round 3
// 20.834 us; speedup vs baseline: 2.1629x; 2.1629x over previous
//
#include <hip/hip_runtime.h>

#define NG  8     // groups (heads)
#define DH  8     // channels per group
#define KS  7
#define PAD 3
#define TH  16    // tile height (output rows per block)
#define TW  32    // tile width (output cols per block)
#define OW  2     // outputs per thread along W
#define TPH 22    // padded tile rows (TH + KS - 1)
#define TPW 38    // padded tile cols (TW + KS - 1)
#define LST 40    // LDS row stride in words (mult of 4; stride%32=8 -> even bank spread)
#define CH  64
#define HH  64
#define WW  64

__device__ __forceinline__ int imin(int a, int b) { return a < b ? a : b; }
__device__ __forceinline__ int imax(int a, int b) { return a > b ? a : b; }

__global__ __launch_bounds__(256, 1)
void saconv_kernel(const float* __restrict__ x,
                   const float* __restrict__ wq,
                   const float* __restrict__ wk,
                   const float* __restrict__ wv,
                   const float* __restrict__ relh,
                   const float* __restrict__ relw,
                   float* __restrict__ out) {
  __shared__ float xs[DH][TPH * LST];   // zero-padded x tile, 27.5 KB
  __shared__ float swq[DH * DH];
  __shared__ float swk[DH * DH];
  __shared__ float swv[DH * DH];
  __shared__ float srel[DH * KS];       // rel table for this group's channels

  const int tx  = threadIdx.x;          // 0..15 (pair of output columns)
  const int ty  = threadIdx.y;          // 0..15 (output row)
  const int tid = ty * 16 + tx;         // 0..255
  const int bz  = blockIdx.z;
  const int b   = bz >> 3;
  const int g   = bz & 7;
  const int h0  = blockIdx.y * TH;
  const int w0  = blockIdx.x * TW;

  // ---- stage weights + rel table ----
  if (tid < DH * DH) swq[tid] = wq[g * DH * DH + tid];
  else if (tid < 2 * DH * DH) swk[tid - 64] = wk[g * DH * DH + tid - 64];
  else if (tid < 3 * DH * DH) swv[tid - 128] = wv[g * DH * DH + tid - 128];
  else if (tid < 3 * DH * DH + DH * KS) {
    int t2 = tid - 192;
    int c = t2 / KS, t = t2 - c * KS;
    int gc = g * DH + c;               // global channel
    srel[t2] = (g < 4) ? relh[gc * KS + t] : relw[(gc - 32) * KS + t];
  }

  // ---- stage zero-padded x tile as float4 chunks ----
  // xs[ci][row*LST + col] = x[b, g*8+ci, h0+row-3, w0+col-3]; cols 0..39 staged (38 used)
  const float* xb = x + (size_t)(b * CH + g * DH) * (HH * WW);
  const int NF4 = DH * TPH * (LST / 4);   // 8*22*10 = 1760 float4 chunks
  #pragma unroll
  for (int kk = 0; kk < 7; kk++) {
    int f = tid + kk * 256;
    if (f < NF4) {
      int ci  = f / (TPH * 10);
      int r   = f - ci * (TPH * 10);
      int row = r / 10;
      int c4  = r - row * 10;
      int yy  = h0 + row - PAD;
      int cy  = imin(imax(yy, 0), HH - 1);
      bool yok = (yy >= 0) & (yy < HH);
      float v[4];
      #pragma unroll
      for (int e = 0; e < 4; e++) {
        int xx = w0 + 4 * c4 + e - PAD;
        int cx = imin(imax(xx, 0), WW - 1);
        bool inb = yok & (xx >= 0) & (xx < WW);
        float t = xb[(ci * HH + cy) * WW + cx];
        v[e] = inb ? t : 0.0f;
      }
      *(float4*)(&xs[ci][row * LST + 4 * c4]) = make_float4(v[0], v[1], v[2], v[3]);
    }
  }
  __syncthreads();

  // ---- q for this thread's 2 outputs, fold: qk = scale*(Wk^T q), rq = scale*(rel^T q) ----
  const float scale = 0.35355339059327373f;  // sqrt(g/Cout) = sqrt(1/8)
  float qk[OW][DH];
  float rq[OW][KS];
  {
    float q_[OW][DH];
    #pragma unroll
    for (int o = 0; o < OW; o++) {
      float xc[DH];
      #pragma unroll
      for (int ci = 0; ci < DH; ci++)
        xc[ci] = xs[ci][(ty + PAD) * LST + 2 * tx + o + PAD];
      #pragma unroll
      for (int c = 0; c < DH; c++) {
        float a = 0.f;
        #pragma unroll
        for (int ci = 0; ci < DH; ci++)
          a = fmaf(swq[c * DH + ci], xc[ci], a);
        q_[o][c] = a;
      }
    }
    #pragma unroll
    for (int o = 0; o < OW; o++)
      #pragma unroll
      for (int ci = 0; ci < DH; ci++) {
        float a = 0.f;
        #pragma unroll
        for (int c = 0; c < DH; c++)
          a = fmaf(q_[o][c], swk[c * DH + ci], a);
        qk[o][ci] = a * scale;
      }
    #pragma unroll
    for (int o = 0; o < OW; o++)
      #pragma unroll
      for (int t = 0; t < KS; t++) {
        float a = 0.f;
        #pragma unroll
        for (int c = 0; c < DH; c++)
          a = fmaf(q_[o][c], srel[c * KS + t], a);
        rq[o][t] = a * scale;
      }
  }

  // ---- window loop: softmax WITHOUT max-shift (logits are O(10), fp32-safe) ----
  const bool useI = (g < 4);   // rel_h half -> rel depends on window row i

  float s[OW], xa[OW][DH];
  #pragma unroll
  for (int o = 0; o < OW; o++) {
    s[o] = 0.f;
    #pragma unroll
    for (int ci = 0; ci < DH; ci++) xa[o][ci] = 0.f;
  }

  #pragma unroll
  for (int i = 0; i < KS; i++) {
    const int rowoff = (ty + i) * LST + 2 * tx;   // 8B-aligned word offset
    // load the 8-word row segment for all 8 channels (4x ds_read_b64 each)
    float xr[DH][8];
    #pragma unroll
    for (int ci = 0; ci < DH; ci++) {
      const float* bp = &xs[ci][rowoff];
      float2 a0 = *(const float2*)(bp);
      float2 a1 = *(const float2*)(bp + 2);
      float2 a2 = *(const float2*)(bp + 4);
      float2 a3 = *(const float2*)(bp + 6);
      xr[ci][0] = a0.x; xr[ci][1] = a0.y; xr[ci][2] = a1.x; xr[ci][3] = a1.y;
      xr[ci][4] = a2.x; xr[ci][5] = a2.y; xr[ci][6] = a3.x; xr[ci][7] = a3.y;
    }

    #pragma unroll
    for (int o = 0; o < OW; o++) {
      float e[KS];
      float se = 0.f;
      #pragma unroll
      for (int j = 0; j < KS; j++) {
        float d = useI ? rq[o][i] : rq[o][j];   // scale pre-folded
        #pragma unroll
        for (int ci = 0; ci < DH; ci++)
          d = fmaf(qk[o][ci], xr[ci][o + j], d);
        e[j] = __expf(d);
        se += e[j];
      }
      s[o] += se;
      #pragma unroll
      for (int ci = 0; ci < DH; ci++) {
        float a = xa[o][ci];
        #pragma unroll
        for (int j = 0; j < KS; j++)
          a = fmaf(e[j], xr[ci][o + j], a);
        xa[o][ci] = a;
      }
    }
  }

  // ---- epilogue: out = Wv * (xa / s), float2 stores ----
  #pragma unroll
  for (int o = 0; o < OW; o++) {
    float inv = 1.0f / s[o];
    #pragma unroll
    for (int ci = 0; ci < DH; ci++) xa[o][ci] *= inv;
  }

  const int h = h0 + ty;
  const int wbase = w0 + 2 * tx;
  #pragma unroll
  for (int c = 0; c < DH; c++) {
    float2 v2;
    {
      float a0 = 0.f, a1 = 0.f;
      #pragma unroll
      for (int ci = 0; ci < DH; ci++) {
        a0 = fmaf(swv[c * DH + ci], xa[0][ci], a0);
        a1 = fmaf(swv[c * DH + ci], xa[1][ci], a1);
      }
      v2.x = a0; v2.y = a1;
    }
    *(float2*)(&out[((size_t)(b * CH + g * DH + c) * HH + h) * WW + wbase]) = v2;
  }
}

extern "C" void kernel_launch(void* const* d_in, const int* in_sizes, int n_in,
                              void* d_out, int out_size, void* d_ws, size_t ws_size,
                              hipStream_t stream) {
  const float* x    = (const float*)d_in[0];
  // d_in[1] = r, unused by the reference computation
  const float* wq   = (const float*)d_in[2];
  const float* wk   = (const float*)d_in[3];
  const float* wv   = (const float*)d_in[4];
  const float* relh = (const float*)d_in[5];
  const float* relw = (const float*)d_in[6];
  float* out = (float*)d_out;

  const int B = in_sizes[0] / (CH * HH * WW);   // 8
  dim3 grid(WW / TW, HH / TH, B * NG);          // 2 x 4 x 64 = 512 blocks
  dim3 block(16, 16, 1);                        // 256 threads = 4 waves
  saconv_kernel<<<grid, block, 0, stream>>>(x, wq, wk, wv, relh, relw, out);
}